// Round 1
// baseline (16419.199 us; speedup 1.0000x reference)
//
#include <hip/hip_runtime.h>
#include <stdint.h>

#define Bsz 16
#define Tn 512
#define Hn 512
#define Vn 32000
#define KIN 1024
#define G4 2048
#define NBLK 256
#define PHASES 513

typedef __attribute__((ext_vector_type(8))) short short8;
typedef __attribute__((ext_vector_type(4))) float f32x4;
typedef __attribute__((ext_vector_type(4))) int i32x4;

__device__ __forceinline__ unsigned short f2bf(float v) {
  unsigned int x = __float_as_uint(v);
  return (unsigned short)((x + 0x7fffu + ((x >> 16) & 1u)) >> 16);  // RNE
}
__device__ __forceinline__ float bf2f(unsigned short u) {
  return __uint_as_float(((unsigned int)u) << 16);
}
__device__ __forceinline__ float aload(const float* p) {
  return __hip_atomic_load(p, __ATOMIC_RELAXED, __HIP_MEMORY_SCOPE_AGENT);
}
__device__ __forceinline__ void astore(float* p, float v) {
  __hip_atomic_store(p, v, __ATOMIC_RELAXED, __HIP_MEMORY_SCOPE_AGENT);
}

// ---------------- Wout f32 -> transposed bf16 hi/lo [V][H] ----------------
__global__ __launch_bounds__(256) void wout_convert(const float* __restrict__ Wout,
                                                    unsigned short* __restrict__ BhT,
                                                    unsigned short* __restrict__ BlT) {
  __shared__ float ts[64][65];
  const int n0 = blockIdx.x * 64;
  const int k0 = blockIdx.y * 64;
  const int tid = threadIdx.x;
  {
    const int c = tid & 63, rq = tid >> 6;
#pragma unroll
    for (int i = 0; i < 16; ++i) {
      const int k = rq * 16 + i;
      ts[k][c] = Wout[(size_t)(k0 + k) * Vn + (n0 + c)];
    }
  }
  __syncthreads();
  {
    const int nl = tid >> 2;          // 0..63
    const int ks = (tid & 3) * 16;    // 0,16,32,48
    unsigned short hb[16], lb[16];
#pragma unroll
    for (int i = 0; i < 16; ++i) {
      const float v = ts[ks + i][nl];
      const unsigned short h = f2bf(v);
      hb[i] = h;
      lb[i] = f2bf(v - bf2f(h));
    }
    const size_t base = (size_t)(n0 + nl) * Hn + (k0 + ks);
    *(i32x4*)&BhT[base]     = *(const i32x4*)&hb[0];
    *(i32x4*)&BhT[base + 8] = *(const i32x4*)&hb[8];
    *(i32x4*)&BlT[base]     = *(const i32x4*)&lb[0];
    *(i32x4*)&BlT[base + 8] = *(const i32x4*)&lb[8];
  }
}

// ---------------- persistent fused 2-layer LSTM scan ----------------
// 256 blocks x 256 threads, 1 block/CU (LDS-forced). blocks 0..127: layer 0,
// 128..255: layer 1 (pipelined one step behind). 513 phases, global barrier each.
// Each block owns 4 hidden units (16 gate columns), weights for [x||h] (1024 rows) in LDS.
__global__ __launch_bounds__(256) void lstm_scan(
    const int* __restrict__ tokens, const float* __restrict__ embed,
    const float* __restrict__ Wg, const float* __restrict__ bg,
    float* __restrict__ hex1, float* __restrict__ hex2,   // [2][16][512] each
    unsigned short* __restrict__ Ah, unsigned short* __restrict__ Al,
    unsigned* __restrict__ cnt, unsigned* __restrict__ gen) {

  extern __shared__ float smem[];
  float* Wl    = smem;                      // [16][1028]  (xor-swizzled along k)
  float* xh    = smem + 16 * 1028;          // [16][1028]  (xor-swizzled along k)
  float* red   = smem + 2 * 16 * 1028;      // [16][16][17]
  float* gates = red + 16 * 16 * 17;        // [16][16]
  float* cst   = gates + 16 * 16;           // [16][4]
  int*   tokl  = (int*)(cst + 16 * 4);      // [16]

  const int tid = threadIdx.x;
  const int bid = blockIdx.x;
  const int layer = bid >> 7;               // 0 or 1
  const int u0 = (bid & 127) * 4;

  // one-time: load W slice (cols = gate*512 + u0 + j), k-swizzled into LDS
  for (int idx = tid; idx < 16 * KIN; idx += 256) {
    const int k = idx >> 4;
    const int c = idx & 15;
    const int col = ((c >> 2) << 9) + u0 + (c & 3);
    const int chunk = k >> 2;
    const int phys = chunk ^ ((chunk >> 4) & 7);
    Wl[c * 1028 + phys * 4 + (k & 3)] =
        Wg[(size_t)layer * KIN * G4 + (size_t)k * G4 + col];
  }
  if (tid < 64) cst[tid] = 0.f;
  __syncthreads();

  const int ksec = tid >> 4;      // 0..15 (64 k each)
  const int bt = (tid >> 2) & 3;  // b group
  const int ct = tid & 3;         // c group
  const int sw = ksec & 7;
  const int chunk0 = ksec << 4;

  for (int ph = 0; ph < PHASES; ++ph) {
    const int t = (layer == 0) ? ph : ph - 1;
    const bool active = (layer == 0) ? (ph < Tn) : (ph >= 1);

    if (active && layer == 0 && tid < 16) tokl[tid] = tokens[tid * Tn + t];
    __syncthreads();

    if (active) {
      // stage xh = [x_t(512) || h_prev(512)] for all 16 b, swizzled
      float* hown = (layer == 0 ? hex1 : hex2) + (((t & 1) ^ 1) * (16 * 512));
      const float* hx1 = hex1 + ((t & 1) * (16 * 512));  // h1[t] for layer 1's x
#pragma unroll 4
      for (int it = 0; it < 16; ++it) {
        const int cid = tid + (it << 8);
        const int b = cid >> 8;
        const int kchunk = cid & 255;
        const int k = kchunk << 2;
        float4 v;
        if (layer == 0) {
          if (k < 512) {
            v = *(const float4*)(embed + (size_t)tokl[b] * Hn + k);
          } else {
            const float* s = hown + b * 512 + (k - 512);
            v.x = aload(s); v.y = aload(s + 1); v.z = aload(s + 2); v.w = aload(s + 3);
          }
        } else {
          const float* s = (k < 512) ? (hx1 + b * 512 + k) : (hown + b * 512 + (k - 512));
          v.x = aload(s); v.y = aload(s + 1); v.z = aload(s + 2); v.w = aload(s + 3);
        }
        const int phys = kchunk ^ ((kchunk >> 4) & 7);
        *(float4*)&xh[b * 1028 + phys * 4] = v;
      }
    }
    __syncthreads();

    if (active) {
      float acc[4][4] = {{0.f,0.f,0.f,0.f},{0.f,0.f,0.f,0.f},{0.f,0.f,0.f,0.f},{0.f,0.f,0.f,0.f}};
#pragma unroll
      for (int it2 = 0; it2 < 16; ++it2) {
        const int phys4 = ((chunk0 | it2) ^ sw) << 2;
        float4 xv[4], wv[4];
#pragma unroll
        for (int jb = 0; jb < 4; ++jb) xv[jb] = *(const float4*)&xh[(bt * 4 + jb) * 1028 + phys4];
#pragma unroll
        for (int jc = 0; jc < 4; ++jc) wv[jc] = *(const float4*)&Wl[(ct * 4 + jc) * 1028 + phys4];
#pragma unroll
        for (int jb = 0; jb < 4; ++jb)
#pragma unroll
          for (int jc = 0; jc < 4; ++jc) {
            acc[jb][jc] += xv[jb].x * wv[jc].x;
            acc[jb][jc] += xv[jb].y * wv[jc].y;
            acc[jb][jc] += xv[jb].z * wv[jc].z;
            acc[jb][jc] += xv[jb].w * wv[jc].w;
          }
      }
#pragma unroll
      for (int jb = 0; jb < 4; ++jb)
#pragma unroll
        for (int jc = 0; jc < 4; ++jc)
          red[ksec * 272 + (bt * 4 + jb) * 17 + (ct * 4 + jc)] = acc[jb][jc];
    }
    __syncthreads();

    if (active) {
      const int b = tid >> 4, c = tid & 15;
      float s = 0.f;
#pragma unroll
      for (int ss = 0; ss < 16; ++ss) s += red[ss * 272 + b * 17 + c];
      const int col = ((c >> 2) << 9) + u0 + (c & 3);
      gates[b * 16 + c] = s + bg[layer * G4 + col];
    }
    __syncthreads();

    if (active && tid < 64) {
      const int b = tid >> 2, j = tid & 3;
      const float iv = gates[b * 16 + j];
      const float fv = gates[b * 16 + 4 + j];
      const float gv = gates[b * 16 + 8 + j];
      const float ov = gates[b * 16 + 12 + j];
      const float si = 1.f / (1.f + expf(-iv));
      const float sf = 1.f / (1.f + expf(-fv));
      const float tg = tanhf(gv);
      const float so = 1.f / (1.f + expf(-ov));
      const float cn = sf * cst[tid] + si * tg;
      cst[tid] = cn;
      const float hn = so * tanhf(cn);
      float* hdst = (layer == 0 ? hex1 : hex2) + (t & 1) * (16 * 512) + b * 512 + (u0 + j);
      astore(hdst, hn);
      if (layer == 1) {
        const size_t r = (size_t)t * 16 + b;
        const unsigned short hbv = f2bf(hn);
        Ah[r * Hn + u0 + j] = hbv;
        Al[r * Hn + u0 + j] = f2bf(hn - bf2f(hbv));
      }
    }

    // device-wide barrier (monotone counter + generation flag)
    __syncthreads();
    if (tid == 0) {
      const unsigned target = (unsigned)(ph + 1);
      const unsigned old =
          __hip_atomic_fetch_add(cnt, 1u, __ATOMIC_ACQ_REL, __HIP_MEMORY_SCOPE_AGENT);
      if (old == target * NBLK - 1u) {
        __hip_atomic_store(gen, target, __ATOMIC_RELEASE, __HIP_MEMORY_SCOPE_AGENT);
      } else {
        while (__hip_atomic_load(gen, __ATOMIC_ACQUIRE, __HIP_MEMORY_SCOPE_AGENT) < target) {
          __builtin_amdgcn_s_sleep(2);
        }
      }
    }
    __syncthreads();
  }
}

// ---------------- projection GEMM: out[b][t][v] = H2 @ Wout + bout ----------
// split-bf16 x3 MFMA (AhBh + AhBl + AlBh), 128x128 tile, BK=32, 4 waves of 64x64.
__global__ __launch_bounds__(256) void proj_gemm(
    const unsigned short* __restrict__ Ah_, const unsigned short* __restrict__ Al_,
    const unsigned short* __restrict__ Bh_, const unsigned short* __restrict__ Bl_,
    const float* __restrict__ bout, float* __restrict__ out) {
  __shared__ unsigned short sAh[128 * 32], sAl[128 * 32], sBh[128 * 32], sBl[128 * 32];
  const int tid = threadIdx.x;
  const int n0 = blockIdx.x * 128;
  const int m0 = blockIdx.y * 128;
  const int lane = tid & 63, w = tid >> 6;
  const int wm = (w & 1) * 64, wn = (w >> 1) * 64;

  f32x4 acc[4][4];
#pragma unroll
  for (int i = 0; i < 4; ++i)
#pragma unroll
    for (int j = 0; j < 4; ++j) acc[i][j] = (f32x4){0.f, 0.f, 0.f, 0.f};

  for (int kt = 0; kt < 16; ++kt) {
    const int k0 = kt * 32;
    __syncthreads();
#pragma unroll
    for (int i = 0; i < 8; ++i) {
      const int chunk = ((i & 1) << 8) + tid;   // 0..511
      const int mrow = chunk >> 2;
      const int kc = chunk & 3;
      const int tsel = i >> 1;
      const unsigned short* gsrc =
          (tsel == 0) ? Ah_ + (size_t)(m0 + mrow) * Hn + k0 + kc * 8 :
          (tsel == 1) ? Al_ + (size_t)(m0 + mrow) * Hn + k0 + kc * 8 :
          (tsel == 2) ? Bh_ + (size_t)(n0 + mrow) * Hn + k0 + kc * 8 :
                        Bl_ + (size_t)(n0 + mrow) * Hn + k0 + kc * 8;
      unsigned short* ldst = (tsel == 0) ? sAh : (tsel == 1) ? sAl : (tsel == 2) ? sBh : sBl;
      *(i32x4*)&ldst[chunk * 8] = *(const i32x4*)gsrc;
    }
    __syncthreads();

    short8 fah[4], fal[4], fbh[4], fbl[4];
    const int rlo = lane & 15, kg = (lane >> 4) * 8;
#pragma unroll
    for (int f = 0; f < 4; ++f) {
      fah[f] = *(const short8*)&sAh[(wm + f * 16 + rlo) * 32 + kg];
      fal[f] = *(const short8*)&sAl[(wm + f * 16 + rlo) * 32 + kg];
      fbh[f] = *(const short8*)&sBh[(wn + f * 16 + rlo) * 32 + kg];
      fbl[f] = *(const short8*)&sBl[(wn + f * 16 + rlo) * 32 + kg];
    }
#pragma unroll
    for (int i = 0; i < 4; ++i)
#pragma unroll
      for (int j = 0; j < 4; ++j) {
        acc[i][j] = __builtin_amdgcn_mfma_f32_16x16x32_bf16(fah[i], fbh[j], acc[i][j], 0, 0, 0);
        acc[i][j] = __builtin_amdgcn_mfma_f32_16x16x32_bf16(fah[i], fbl[j], acc[i][j], 0, 0, 0);
        acc[i][j] = __builtin_amdgcn_mfma_f32_16x16x32_bf16(fal[i], fbh[j], acc[i][j], 0, 0, 0);
      }
  }

  // epilogue: row r = t*16+b  ->  out[b*T*V + t*V + n], add bout
#pragma unroll
  for (int j = 0; j < 4; ++j) {
    const int n = n0 + wn + j * 16 + (lane & 15);
    const float bv = bout[n];
#pragma unroll
    for (int i = 0; i < 4; ++i) {
#pragma unroll
      for (int r = 0; r < 4; ++r) {
        const int m = m0 + wm + i * 16 + ((lane >> 4) * 4) + r;
        out[(size_t)(m & 15) * ((size_t)Tn * Vn) + (size_t)(m >> 4) * Vn + n] =
            acc[i][j][r] + bv;
      }
    }
  }
}

extern "C" void kernel_launch(void* const* d_in, const int* in_sizes, int n_in,
                              void* d_out, int out_size, void* d_ws, size_t ws_size,
                              hipStream_t stream) {
  const int*   tokens = (const int*)d_in[0];
  const float* embed  = (const float*)d_in[1];
  const float* W      = (const float*)d_in[2];
  const float* bias   = (const float*)d_in[3];
  const float* Wout   = (const float*)d_in[4];
  const float* bout   = (const float*)d_in[5];
  float* out = (float*)d_out;

  char* ws = (char*)d_ws;
  unsigned* cnt = (unsigned*)ws;                    // monotone arrival counter
  unsigned* gen = (unsigned*)(ws + 64);             // generation flag (own line)
  float* hex1 = (float*)(ws + 256);                 // [2][16][512]
  float* hex2 = (float*)(ws + 256 + 65536);         // [2][16][512]
  unsigned short* Ah  = (unsigned short*)(ws + 256 + 2 * 65536);
  unsigned short* Al  = Ah + (size_t)8192 * 512;
  unsigned short* BhT = Al + (size_t)8192 * 512;
  unsigned short* BlT = BhT + (size_t)32000 * 512;
  // total ws use: ~82.4 MB

  // zero barrier state + h exchange buffers (fresh every launch -> deterministic)
  hipMemsetAsync(d_ws, 0, 256 + 2 * 65536, stream);

  wout_convert<<<dim3(500, 8), 256, 0, stream>>>(Wout, BhT, BlT);

  const size_t ldsbytes =
      (size_t)(2 * 16 * 1028 + 16 * 16 * 17 + 16 * 16 + 16 * 4) * 4 + 16 * 4;  // 150336
  (void)hipFuncSetAttribute((const void*)lstm_scan,
                            hipFuncAttributeMaxDynamicSharedMemorySize, (int)ldsbytes);
  lstm_scan<<<NBLK, 256, ldsbytes, stream>>>(tokens, embed, W, bias,
                                             hex1, hex2, Ah, Al, cnt, gen);

  proj_gemm<<<dim3(250, 64), 256, 0, stream>>>(Ah, Al, BhT, BlT, bout, out);
}